// Round 1
// baseline (311.591 us; speedup 1.0000x reference)
//
#include <hip/hip_runtime.h>
#include <math.h>

#define NV 20
#define NC 64
#define NSTATES (1u << 20)
#define TOPK 10
#define NB1 1024         // stage-1 top-k blocks
#define SEG 1024         // elements per stage-1 block
#define NCAND (NB1 * TOPK)

// ---------------------------------------------------------------------------
// costs[i] = sum_c relu(bits(i)·C_c - 1)^2 + 0.1*popcount(i)
// bits MSB-first: bits[i][v] = (i >> (19-v)) & 1, so bit position p maps to
// constraint column (19-p).
// Strategy: 8-bit LDS table over bits 0..7 (with the -1 folded in) + per-
// 256-state-group block-uniform high part vh[c] over bits 8..19.
// Also zeroes the 3 double sumsq accumulators (block 0).
// ---------------------------------------------------------------------------
__global__ __launch_bounds__(256) void k_costs(const float* __restrict__ C,
                                               float* __restrict__ costs,
                                               double* __restrict__ scal) {
    __shared__ float T[NC * 256];   // 64 KiB, layout [c][m] -> lane m fastest
    __shared__ float vh[NC];
    const int tid = threadIdx.x;

    if (blockIdx.x == 0 && tid < 8) scal[tid] = 0.0;

    // build lower-8-bit table (bits p=0..7 -> columns 19..12), -1 folded in
    for (int e = tid; e < NC * 256; e += 256) {
        int c = e >> 8, m = e & 255;
        float s = -1.0f;
        #pragma unroll
        for (int p = 0; p < 8; ++p)
            if ((m >> p) & 1) s += C[c * NV + (NV - 1 - p)];
        T[e] = s;
    }

    const int G = 4;  // groups of 256 states per block
    for (int g = 0; g < G; ++g) {
        __syncthreads();
        unsigned base = ((unsigned)blockIdx.x * G + (unsigned)g) << 8;
        if (tid < NC) {
            float s = 0.0f;
            #pragma unroll
            for (int p = 8; p < NV; ++p)
                if ((base >> p) & 1) s += C[tid * NV + (NV - 1 - p)];
            vh[tid] = s;
        }
        __syncthreads();
        unsigned i = base + (unsigned)tid;
        float cost = 0.1f * (float)__popc(i);
        #pragma unroll
        for (int c = 0; c < NC; ++c) {
            float r = vh[c] + T[(c << 8) | tid];   // tid == (i & 255)
            r = fmaxf(r, 0.0f);
            cost = fmaf(r, r, cost);
        }
        costs[i] = cost;
    }
}

// ---------------------------------------------------------------------------
// phase: out[i] = amp_in(i) * cos(gamma[layer]*costs[i])
// layer 0: amp_in = 1/sqrt(2^20) = 2^-10 exactly (prev_sumsq == nullptr)
// layer>0: amp_in = in[i] * 1/sqrt(prev_sumsq)  (deferred normalization)
// ---------------------------------------------------------------------------
__global__ __launch_bounds__(256) void k_phase(const float* __restrict__ in,
                                               const float* __restrict__ costs,
                                               float* __restrict__ out,
                                               const float* __restrict__ gamma,
                                               int layer,
                                               const double* __restrict__ prev_sumsq) {
    unsigned i = blockIdx.x * 256u + threadIdx.x;
    float g = gamma[layer];
    float amp;
    if (prev_sumsq) {
        float scale = (float)(1.0 / sqrt(*prev_sumsq));
        amp = in[i] * scale;
    } else {
        amp = 0x1p-10f;  // 1/1024
    }
    out[i] = amp * cosf(g * costs[i]);
}

// ---------------------------------------------------------------------------
// mixer: out[i] = a[i] + 0.1*sin(beta[layer]) * sum_{p=19..0} a[i ^ (1<<p)]
// (sum order matches the reference's flip loop: axis 0 first -> bit 19 first)
// Accumulates sum of squares of out into *sumsq (double) for normalization.
// ---------------------------------------------------------------------------
__global__ __launch_bounds__(256) void k_mix(const float* __restrict__ a,
                                             float* __restrict__ out,
                                             const float* __restrict__ beta,
                                             int layer,
                                             double* __restrict__ sumsq) {
    __shared__ double rs[256];
    unsigned i = blockIdx.x * 256u + threadIdx.x;
    float s = 0.1f * sinf(beta[layer]);
    float nb = 0.0f;
    #pragma unroll
    for (int p = NV - 1; p >= 0; --p) nb += a[i ^ (1u << p)];
    float m = a[i] + s * nb;
    out[i] = m;

    int tid = threadIdx.x;
    rs[tid] = (double)m * (double)m;
    __syncthreads();
    for (int off = 128; off > 0; off >>= 1) {
        if (tid < off) rs[tid] += rs[tid + off];
        __syncthreads();
    }
    if (tid == 0) atomicAdd(sumsq, rs[0]);
}

// probs[i] = (b[i] / sqrt(sumsq))^2   (safe in-place when probs == b)
__global__ __launch_bounds__(256) void k_probs(const float* __restrict__ b,
                                               const double* __restrict__ sumsq,
                                               float* __restrict__ probs) {
    unsigned i = blockIdx.x * 256u + threadIdx.x;
    float scale = (float)(1.0 / sqrt(*sumsq));
    float amp = b[i] * scale;
    probs[i] = amp * amp;
}

// ---------------------------------------------------------------------------
// top-k stage 1: each block finds the top-10 of its 1024-element segment.
// Keys pack (value_bits << 32) | (0xFFFFFFFF - global_idx): max key == max
// value, ties -> lower index, matching jax.lax.top_k.
// ---------------------------------------------------------------------------
__global__ __launch_bounds__(256) void k_top1(const float* __restrict__ probs,
                                              unsigned long long* __restrict__ cand) {
    __shared__ float v[SEG];
    __shared__ unsigned long long red[256];
    unsigned base = blockIdx.x * SEG;
    int tid = threadIdx.x;
    for (int j = tid; j < SEG; j += 256) v[j] = probs[base + j];
    __syncthreads();
    for (int r = 0; r < TOPK; ++r) {
        unsigned long long best = 0ull;
        for (int j = tid; j < SEG; j += 256) {
            float val = v[j];
            if (val >= 0.0f) {
                unsigned long long k =
                    ((unsigned long long)__float_as_uint(val) << 32) |
                    (unsigned long long)(0xFFFFFFFFu - (base + (unsigned)j));
                if (k > best) best = k;
            }
        }
        red[tid] = best;
        __syncthreads();
        for (int off = 128; off > 0; off >>= 1) {
            if (tid < off) { if (red[tid + off] > red[tid]) red[tid] = red[tid + off]; }
            __syncthreads();
        }
        if (tid == 0) {
            unsigned long long w = red[0];
            cand[blockIdx.x * TOPK + r] = w;
            unsigned gidx = 0xFFFFFFFFu - (unsigned)(w & 0xFFFFFFFFull);
            v[gidx - base] = -1.0f;  // exclude from later rounds
        }
        __syncthreads();
    }
}

// ---------------------------------------------------------------------------
// top-k stage 2 (single block): merge 10240 candidates -> global top-10 in
// order, then emit top_assignments, assignment_costs, optimal_{assignment,cost}
// ---------------------------------------------------------------------------
__global__ __launch_bounds__(1024) void k_top2(const unsigned long long* __restrict__ cand,
                                               const float* __restrict__ costs,
                                               float* __restrict__ d_out) {
    __shared__ unsigned long long ck[NCAND];   // 80 KiB
    __shared__ unsigned long long red[1024];
    __shared__ unsigned topi[TOPK];
    __shared__ float topc[TOPK];
    int tid = threadIdx.x;
    for (int j = tid; j < NCAND; j += 1024) ck[j] = cand[j];
    __syncthreads();
    for (int r = 0; r < TOPK; ++r) {
        unsigned long long best = 0ull;
        int bj = -1;
        for (int j = tid; j < NCAND; j += 1024)
            if (ck[j] > best) { best = ck[j]; bj = j; }
        red[tid] = best;
        __syncthreads();
        for (int off = 512; off > 0; off >>= 1) {
            if (tid < off) { if (red[tid + off] > red[tid]) red[tid] = red[tid + off]; }
            __syncthreads();
        }
        unsigned long long w = red[0];
        if (bj >= 0 && best == w) {   // keys are unique: exactly one thread
            ck[bj] = 0ull;
            topi[r] = 0xFFFFFFFFu - (unsigned)(w & 0xFFFFFFFFull);
        }
        __syncthreads();
    }
    const unsigned S = NSTATES;
    if (tid < TOPK * NV) {
        int k = tid / NV, vv = tid % NV;
        unsigned gi = topi[k];
        d_out[21 + S + (unsigned)tid] = (float)((gi >> (NV - 1 - vv)) & 1u);
    }
    if (tid < TOPK) {
        float cst = costs[topi[tid]];
        topc[tid] = cst;
        d_out[21 + S + TOPK * NV + (unsigned)tid] = cst;
    }
    __syncthreads();
    if (tid == 0) {
        int best = 0;
        for (int k = 1; k < TOPK; ++k)
            if (topc[k] < topc[best]) best = k;   // first-min, like jnp.argmin
        unsigned gi = topi[best];
        for (int vv = 0; vv < NV; ++vv)
            d_out[vv] = (float)((gi >> (NV - 1 - vv)) & 1u);
        d_out[NV] = topc[best];
    }
}

extern "C" void kernel_launch(void* const* d_in, const int* in_sizes, int n_in,
                              void* d_out_, int out_size, void* d_ws, size_t ws_size,
                              hipStream_t stream) {
    (void)in_sizes; (void)n_in; (void)out_size;
    const float* C     = (const float*)d_in[0];
    const float* beta  = (const float*)d_in[1];
    const float* gamma = (const float*)d_in[2];
    float* out = (float*)d_out_;
    char* ws = (char*)d_ws;
    const size_t S4 = (size_t)NSTATES * sizeof(float);

    double* scal = (double*)ws;                                  // 3 doubles used
    unsigned long long* cand = (unsigned long long*)(ws + 256);  // 80 KiB
    float* costs = (float*)(ws + 131072);
    float* A     = (float*)(ws + 131072 + S4);
    float* B;
    const size_t need_full = 131072 + 3 * S4;  // ~12.1 MiB
    if (ws_size >= need_full) {
        B = (float*)(ws + 131072 + 2 * S4);
    } else {
        B = out + 21;  // fall back to probs region of d_out as scratch
    }
    float* probs = out + 21;

    k_costs<<<NSTATES / 1024, 256, 0, stream>>>(C, costs, scal);

    // layer 0
    k_phase<<<NSTATES / 256, 256, 0, stream>>>(nullptr, costs, A, gamma, 0, nullptr);
    k_mix  <<<NSTATES / 256, 256, 0, stream>>>(A, B, beta, 0, scal + 0);
    // layer 1
    k_phase<<<NSTATES / 256, 256, 0, stream>>>(B, costs, A, gamma, 1, scal + 0);
    k_mix  <<<NSTATES / 256, 256, 0, stream>>>(A, B, beta, 1, scal + 1);
    // layer 2
    k_phase<<<NSTATES / 256, 256, 0, stream>>>(B, costs, A, gamma, 2, scal + 1);
    k_mix  <<<NSTATES / 256, 256, 0, stream>>>(A, B, beta, 2, scal + 2);

    k_probs<<<NSTATES / 256, 256, 0, stream>>>(B, scal + 2, probs);

    k_top1<<<NB1, 256, 0, stream>>>(probs, cand);
    k_top2<<<1, 1024, 0, stream>>>(cand, costs, out);
}

// Round 2
// 135.316 us; speedup vs baseline: 2.3027x; 2.3027x over previous
//
#include <hip/hip_runtime.h>
#include <math.h>

#define NV 20
#define NC 64
#define NSTATES (1u << 20)
#define TOPK 10
#define NB1 256          // stage-1 blocks
#define SEG 4096         // elements per stage-1 block
#define NCAND (NB1 * TOPK)   // 2560

// ---------------------------------------------------------------------------
// costs[i] = sum_c relu(bits(i)·C_c - 1)^2 + 0.1*popcount(i)
// bits MSB-first: bit position p of i maps to constraint column (19-p).
// 2^17 threads, 8 states each. Per thread: base[c] (c=0..63, in 16 float4
// regs) = -1 + sum over i-bits 3..19 (from t) of C; per state add the
// low-3-bit partial from a 2KB LDS table, then relu^2-accumulate c-ascending
// (same accumulation order as the R1 kernel that validated at 3e-8).
// Also zeroes the sumsq accumulators (block 0).
// ---------------------------------------------------------------------------
__global__ __launch_bounds__(256) void k_costs(const float* __restrict__ C,
                                               float* __restrict__ costs,
                                               double* __restrict__ scal) {
    __shared__ float CT[NV][NC];    // CT[j][c] = C[c][j], 5 KB
    __shared__ float lowT[8][NC];   // low 3 bits (cols 19,18,17), 2 KB
    const int tid = threadIdx.x;

    if (blockIdx.x == 0 && tid < 8) scal[tid] = 0.0;

    for (int e = tid; e < NC * NV; e += 256) {
        int c = e / NV, j = e % NV;
        CT[j][c] = C[e];
    }
    for (int e = tid; e < 8 * NC; e += 256) {
        int m = e >> 6, c = e & 63;
        float v = 0.0f;
        if (m & 1) v += C[c * NV + 19];
        if (m & 2) v += C[c * NV + 18];
        if (m & 4) v += C[c * NV + 17];
        lowT[m][c] = v;
    }
    __syncthreads();

    unsigned t = blockIdx.x * 256u + (unsigned)tid;   // < 2^17

    float4 b[16];
    #pragma unroll
    for (int q = 0; q < 16; ++q) b[q] = make_float4(-1.f, -1.f, -1.f, -1.f);
    #pragma unroll
    for (int k = 0; k < 17; ++k) {
        float bf = (float)((t >> k) & 1u);           // i-bit (k+3) -> col 16-k
        const float4* row = (const float4*)(&CT[16 - k][0]);
        #pragma unroll
        for (int q = 0; q < 16; ++q) {
            float4 cv = row[q];
            b[q].x = fmaf(bf, cv.x, b[q].x);
            b[q].y = fmaf(bf, cv.y, b[q].y);
            b[q].z = fmaf(bf, cv.z, b[q].z);
            b[q].w = fmaf(bf, cv.w, b[q].w);
        }
    }

    float res[8];
    #pragma unroll
    for (int s = 0; s < 8; ++s) {
        unsigned i = t * 8u + (unsigned)s;
        float cost = 0.1f * (float)__popc(i);
        const float4* lrow = (const float4*)(&lowT[s][0]);
        #pragma unroll
        for (int q = 0; q < 16; ++q) {
            float4 lv = lrow[q];
            float4 v;
            v.x = b[q].x + lv.x; v.y = b[q].y + lv.y;
            v.z = b[q].z + lv.z; v.w = b[q].w + lv.w;
            float r;
            r = fmaxf(v.x, 0.f); cost = fmaf(r, r, cost);
            r = fmaxf(v.y, 0.f); cost = fmaf(r, r, cost);
            r = fmaxf(v.z, 0.f); cost = fmaf(r, r, cost);
            r = fmaxf(v.w, 0.f); cost = fmaf(r, r, cost);
        }
        res[s] = cost;
    }
    float4* co = (float4*)(costs + (size_t)t * 8u);
    co[0] = make_float4(res[0], res[1], res[2], res[3]);
    co[1] = make_float4(res[4], res[5], res[6], res[7]);
}

// ---------------------------------------------------------------------------
// Fused phase+mixer, one kernel per layer.
// phase(j) = prev[j]*scale*cos(g*costs[j])  (layer 0: 2^-10*cos(g*costs[j]))
// out[i]   = phase(i) + s * sum_{p=19..0} phase(i ^ (1<<p))   (p descending,
// matching the R1 order). Per-block sumsq of out -> scal[LAYER] (atomic).
// float4-vectorized: p>=2 neighbors are whole-quad XORs, p=0,1 are swizzles
// of the own quad. AL=false uses scalar access for the possibly-unaligned
// array (d_out+21 fallback).
// ---------------------------------------------------------------------------
template <int LAYER, bool AL>
__global__ __launch_bounds__(256) void k_mixer(const float* __restrict__ costs,
                                               const float* __restrict__ prev,
                                               float* __restrict__ outp,
                                               const float* __restrict__ gamma,
                                               const float* __restrict__ beta,
                                               double* __restrict__ scal) {
    unsigned i4 = blockIdx.x * 256u + threadIdx.x;   // float4 index < 2^18
    float g = gamma[LAYER];
    float s = 0.1f * sinf(beta[LAYER]);
    float scale;
    if (LAYER == 0) scale = 0x1p-10f;
    else            scale = (float)(1.0 / sqrt(scal[LAYER - 1]));
    const float4* c4p = (const float4*)costs;

    auto phase4 = [&](unsigned j4) -> float4 {
        float4 c = c4p[j4];
        float4 p;
        if (LAYER == 0) {
            p.x = scale * cosf(g * c.x);
            p.y = scale * cosf(g * c.y);
            p.z = scale * cosf(g * c.z);
            p.w = scale * cosf(g * c.w);
        } else {
            float4 a;
            if (AL) {
                a = ((const float4*)prev)[j4];
            } else {
                a.x = prev[4u * j4 + 0]; a.y = prev[4u * j4 + 1];
                a.z = prev[4u * j4 + 2]; a.w = prev[4u * j4 + 3];
            }
            p.x = (a.x * scale) * cosf(g * c.x);
            p.y = (a.y * scale) * cosf(g * c.y);
            p.z = (a.z * scale) * cosf(g * c.z);
            p.w = (a.w * scale) * cosf(g * c.w);
        }
        return p;
    };

    float4 nb = make_float4(0.f, 0.f, 0.f, 0.f);
    #pragma unroll
    for (int p = 19; p >= 2; --p) {
        unsigned j4 = i4 ^ (1u << (p - 2));
        float4 ph = phase4(j4);
        nb.x += ph.x; nb.y += ph.y; nb.z += ph.z; nb.w += ph.w;
    }
    float4 own = phase4(i4);
    // p = 1: element e gets own element e^2
    nb.x += own.z; nb.y += own.w; nb.z += own.x; nb.w += own.y;
    // p = 0: element e gets own element e^1
    nb.x += own.y; nb.y += own.x; nb.z += own.w; nb.w += own.z;

    float4 m;
    m.x = fmaf(s, nb.x, own.x);
    m.y = fmaf(s, nb.y, own.y);
    m.z = fmaf(s, nb.z, own.z);
    m.w = fmaf(s, nb.w, own.w);

    if (AL) {
        ((float4*)outp)[i4] = m;
    } else {
        outp[4u * i4 + 0] = m.x; outp[4u * i4 + 1] = m.y;
        outp[4u * i4 + 2] = m.z; outp[4u * i4 + 3] = m.w;
    }

    double ss = (double)m.x * m.x + (double)m.y * m.y +
                (double)m.z * m.z + (double)m.w * m.w;
    #pragma unroll
    for (int off = 32; off > 0; off >>= 1) ss += __shfl_down(ss, off);
    __shared__ double dpart[4];
    int wid = threadIdx.x >> 6;
    if ((threadIdx.x & 63) == 0) dpart[wid] = ss;
    __syncthreads();
    if (threadIdx.x == 0)
        atomicAdd(&scal[LAYER], dpart[0] + dpart[1] + dpart[2] + dpart[3]);
}

// ---------------------------------------------------------------------------
// Fused probs + top-k stage 1. 256 blocks x 256 threads, 16 elems/thread.
// probs[i] = (a[i]*scale)^2 written to d_out; per-segment top-10 via packed
// (valbits<<32)|(~idx) u64 keys held in registers, wave-shfl reduction.
// ---------------------------------------------------------------------------
__global__ __launch_bounds__(256) void k_ptop1(const float* __restrict__ A,
                                               const double* __restrict__ scal2,
                                               float* __restrict__ probs_out,
                                               unsigned long long* __restrict__ cand) {
    __shared__ unsigned long long warr[4];
    const int tid = threadIdx.x;
    unsigned b4 = blockIdx.x * 1024u;   // float4 base (SEG/4)
    float scale = (float)(1.0 / sqrt(*scal2));
    const float4* a4 = (const float4*)A;

    unsigned long long k[16];
    #pragma unroll
    for (int u = 0; u < 4; ++u) {
        unsigned j4 = b4 + (unsigned)tid + 256u * u;
        float4 v = a4[j4];
        float4 p;
        p.x = v.x * scale; p.x *= p.x;
        p.y = v.y * scale; p.y *= p.y;
        p.z = v.z * scale; p.z *= p.z;
        p.w = v.w * scale; p.w *= p.w;
        unsigned e0 = 4u * j4;
        probs_out[e0 + 0] = p.x; probs_out[e0 + 1] = p.y;
        probs_out[e0 + 2] = p.z; probs_out[e0 + 3] = p.w;
        k[4 * u + 0] = ((unsigned long long)__float_as_uint(p.x) << 32) | (unsigned long long)(0xFFFFFFFFu - (e0 + 0));
        k[4 * u + 1] = ((unsigned long long)__float_as_uint(p.y) << 32) | (unsigned long long)(0xFFFFFFFFu - (e0 + 1));
        k[4 * u + 2] = ((unsigned long long)__float_as_uint(p.z) << 32) | (unsigned long long)(0xFFFFFFFFu - (e0 + 2));
        k[4 * u + 3] = ((unsigned long long)__float_as_uint(p.w) << 32) | (unsigned long long)(0xFFFFFFFFu - (e0 + 3));
    }

    for (int r = 0; r < TOPK; ++r) {
        unsigned long long loc = 0ull;
        #pragma unroll
        for (int j = 0; j < 16; ++j) if (k[j] > loc) loc = k[j];
        #pragma unroll
        for (int off = 32; off > 0; off >>= 1) {
            unsigned long long o = __shfl_down(loc, off);
            if (o > loc) loc = o;
        }
        if ((tid & 63) == 0) warr[tid >> 6] = loc;
        __syncthreads();
        unsigned long long win = warr[0];
        if (warr[1] > win) win = warr[1];
        if (warr[2] > win) win = warr[2];
        if (warr[3] > win) win = warr[3];
        __syncthreads();
        #pragma unroll
        for (int j = 0; j < 16; ++j) if (k[j] == win) k[j] = 0ull;
        if (tid == 0) cand[blockIdx.x * TOPK + r] = win;
    }
}

// ---------------------------------------------------------------------------
// top-k stage 2 (single block, 1024 threads): merge 2560 candidates, emit
// top_assignments, assignment_costs, optimal_{assignment,cost}.
// ---------------------------------------------------------------------------
__global__ __launch_bounds__(1024) void k_top2(const unsigned long long* __restrict__ cand,
                                               const float* __restrict__ costs,
                                               float* __restrict__ out) {
    __shared__ unsigned long long warr[16];
    __shared__ unsigned topi[TOPK];
    __shared__ float topc[TOPK];
    const int tid = threadIdx.x;

    unsigned long long k[3] = {0ull, 0ull, 0ull};
    #pragma unroll
    for (int u = 0; u < 3; ++u) {
        int j = tid + 1024 * u;
        if (j < NCAND) k[u] = cand[j];
    }

    for (int r = 0; r < TOPK; ++r) {
        unsigned long long loc = k[0];
        if (k[1] > loc) loc = k[1];
        if (k[2] > loc) loc = k[2];
        #pragma unroll
        for (int off = 32; off > 0; off >>= 1) {
            unsigned long long o = __shfl_down(loc, off);
            if (o > loc) loc = o;
        }
        if ((tid & 63) == 0) warr[tid >> 6] = loc;
        __syncthreads();
        unsigned long long win = warr[0];
        #pragma unroll
        for (int w = 1; w < 16; ++w) if (warr[w] > win) win = warr[w];
        if (k[0] == win) k[0] = 0ull;
        if (k[1] == win) k[1] = 0ull;
        if (k[2] == win) k[2] = 0ull;
        if (tid == 0) topi[r] = 0xFFFFFFFFu - (unsigned)(win & 0xFFFFFFFFull);
        __syncthreads();
    }

    const unsigned S = NSTATES;
    if (tid < TOPK * NV) {
        int kk = tid / NV, vv = tid % NV;
        out[21 + S + (unsigned)tid] = (float)((topi[kk] >> (NV - 1 - vv)) & 1u);
    }
    if (tid < TOPK) {
        float c = costs[topi[tid]];
        topc[tid] = c;
        out[21 + S + TOPK * NV + (unsigned)tid] = c;
    }
    __syncthreads();
    if (tid == 0) {
        int best = 0;
        for (int kk = 1; kk < TOPK; ++kk)
            if (topc[kk] < topc[best]) best = kk;
        unsigned gi = topi[best];
        for (int vv = 0; vv < NV; ++vv)
            out[vv] = (float)((gi >> (NV - 1 - vv)) & 1u);
        out[NV] = topc[best];
    }
}

extern "C" void kernel_launch(void* const* d_in, const int* in_sizes, int n_in,
                              void* d_out_, int out_size, void* d_ws, size_t ws_size,
                              hipStream_t stream) {
    (void)in_sizes; (void)n_in; (void)out_size;
    const float* C     = (const float*)d_in[0];
    const float* beta  = (const float*)d_in[1];
    const float* gamma = (const float*)d_in[2];
    float* out = (float*)d_out_;
    char* ws = (char*)d_ws;
    const size_t S4 = (size_t)NSTATES * sizeof(float);

    double* scal = (double*)ws;                                   // 8 doubles
    unsigned long long* cand = (unsigned long long*)(ws + 1024);  // 20 KB
    float* costs = (float*)(ws + 32768);
    float* A     = (float*)(ws + 32768 + S4);
    const size_t need_full = 32768 + 3 * S4;
    bool wsbig = (ws_size >= need_full);
    float* B = wsbig ? (float*)(ws + 32768 + 2 * S4) : (out + 21);
    float* probs = out + 21;

    k_costs<<<512, 256, 0, stream>>>(C, costs, scal);

    // layer 0: phase from costs only -> A
    k_mixer<0, true><<<1024, 256, 0, stream>>>(costs, nullptr, A, gamma, beta, scal);
    // layer 1: A -> B (B may be the unaligned d_out+21 region)
    if (wsbig) k_mixer<1, true ><<<1024, 256, 0, stream>>>(costs, A, B, gamma, beta, scal);
    else       k_mixer<1, false><<<1024, 256, 0, stream>>>(costs, A, B, gamma, beta, scal);
    // layer 2: B -> A
    if (wsbig) k_mixer<2, true ><<<1024, 256, 0, stream>>>(costs, B, A, gamma, beta, scal);
    else       k_mixer<2, false><<<1024, 256, 0, stream>>>(costs, B, A, gamma, beta, scal);

    k_ptop1<<<NB1, 256, 0, stream>>>(A, scal + 2, probs, cand);
    k_top2<<<1, 1024, 0, stream>>>(cand, costs, out);
}

// Round 3
// 112.628 us; speedup vs baseline: 2.7665x; 1.2014x over previous
//
#include <hip/hip_runtime.h>
#include <math.h>

#define NV 20
#define NC 64
#define NSTATES (1u << 20)
#define TOPK 10
#define NB1 256              // stage-1 blocks
#define NCAND (NB1 * TOPK)   // 2560

// ---------------------------------------------------------------------------
// costs[i] = sum_c relu(bits(i)·C_c - 1)^2 + 0.1*popcount(i)
// Also emits ph0[i] = 2^-10 * cos(gamma0 * costs[i])  (layer-0 phase array)
// and zeroes the sumsq accumulators + the top-k ticket counter.
// 2^17 threads x 8 states; base dot over bits 3..19 in 16 float4 regs fed by
// LDS C^T broadcasts; low-3-bit LDS table; c-ascending relu^2 accumulation
// (identical order to the R1/R2 kernels that validated at 3e-8).
// ---------------------------------------------------------------------------
__global__ __launch_bounds__(256) void k_costs(const float* __restrict__ C,
                                               float* __restrict__ costs,
                                               float* __restrict__ ph0,
                                               const float* __restrict__ gamma,
                                               double* __restrict__ scal,
                                               unsigned* __restrict__ ctr) {
    __shared__ float CT[NV][NC];    // CT[j][c] = C[c][j], 5 KB
    __shared__ float lowT[8][NC];   // low 3 bits (cols 19,18,17), 2 KB
    const int tid = threadIdx.x;

    if (blockIdx.x == 0) {
        if (tid < 8) scal[tid] = 0.0;
        if (tid == 8) *ctr = 0u;
    }

    for (int e = tid; e < NC * NV; e += 256) {
        int c = e / NV, j = e % NV;
        CT[j][c] = C[e];
    }
    for (int e = tid; e < 8 * NC; e += 256) {
        int m = e >> 6, c = e & 63;
        float v = 0.0f;
        if (m & 1) v += C[c * NV + 19];
        if (m & 2) v += C[c * NV + 18];
        if (m & 4) v += C[c * NV + 17];
        lowT[m][c] = v;
    }
    __syncthreads();

    unsigned t = blockIdx.x * 256u + (unsigned)tid;   // < 2^17
    float g0 = gamma[0];

    float4 b[16];
    #pragma unroll
    for (int q = 0; q < 16; ++q) b[q] = make_float4(-1.f, -1.f, -1.f, -1.f);
    #pragma unroll
    for (int k = 0; k < 17; ++k) {
        float bf = (float)((t >> k) & 1u);           // i-bit (k+3) -> col 16-k
        const float4* row = (const float4*)(&CT[16 - k][0]);
        #pragma unroll
        for (int q = 0; q < 16; ++q) {
            float4 cv = row[q];
            b[q].x = fmaf(bf, cv.x, b[q].x);
            b[q].y = fmaf(bf, cv.y, b[q].y);
            b[q].z = fmaf(bf, cv.z, b[q].z);
            b[q].w = fmaf(bf, cv.w, b[q].w);
        }
    }

    float res[8], ph[8];
    #pragma unroll
    for (int s = 0; s < 8; ++s) {
        unsigned i = t * 8u + (unsigned)s;
        float cost = 0.1f * (float)__popc(i);
        const float4* lrow = (const float4*)(&lowT[s][0]);
        #pragma unroll
        for (int q = 0; q < 16; ++q) {
            float4 lv = lrow[q];
            float4 v;
            v.x = b[q].x + lv.x; v.y = b[q].y + lv.y;
            v.z = b[q].z + lv.z; v.w = b[q].w + lv.w;
            float r;
            r = fmaxf(v.x, 0.f); cost = fmaf(r, r, cost);
            r = fmaxf(v.y, 0.f); cost = fmaf(r, r, cost);
            r = fmaxf(v.z, 0.f); cost = fmaf(r, r, cost);
            r = fmaxf(v.w, 0.f); cost = fmaf(r, r, cost);
        }
        res[s] = cost;
        ph[s] = 0x1p-10f * cosf(g0 * cost);
    }
    float4* co = (float4*)(costs + (size_t)t * 8u);
    co[0] = make_float4(res[0], res[1], res[2], res[3]);
    co[1] = make_float4(res[4], res[5], res[6], res[7]);
    float4* po = (float4*)(ph0 + (size_t)t * 8u);
    po[0] = make_float4(ph[0], ph[1], ph[2], ph[3]);
    po[1] = make_float4(ph[4], ph[5], ph[6], ph[7]);
}

// ---------------------------------------------------------------------------
// Mixer over a PRE-PHASED array pin (pin[j] already includes amp*cos for this
// layer, up to the uniform 1/norm factor of the previous layer):
//   m[i]  = prevscale * (pin[i] + s*sum_{p=19..0} pin[i^(1<<p)])
//   sumsq += m^2  -> scal[LAYER]
//   LAYER<2:  pout[i] = m[i] * cos(gamma[LAYER+1]*costs[i])  (next pre-phase)
//   LAYER==2: pout[i] = m[i]
// Neighbor-sum order matches R2 (p descending; p=1,0 are in-quad swizzles).
// ---------------------------------------------------------------------------
template <int LAYER, bool ALIN, bool ALOUT>
__global__ __launch_bounds__(256) void k_mix(const float* __restrict__ pin,
                                             const float* __restrict__ costs,
                                             float* __restrict__ pout,
                                             const float* __restrict__ gamma,
                                             const float* __restrict__ beta,
                                             double* __restrict__ scal) {
    unsigned i4 = blockIdx.x * 256u + threadIdx.x;   // float4 index < 2^18
    float s = 0.1f * sinf(beta[LAYER]);
    float prevscale = (LAYER == 0) ? 1.0f : (float)(1.0 / sqrt(scal[LAYER - 1]));

    auto ld4 = [&](unsigned j4) -> float4 {
        if (ALIN) return ((const float4*)pin)[j4];
        float4 a;
        a.x = pin[4u * j4 + 0]; a.y = pin[4u * j4 + 1];
        a.z = pin[4u * j4 + 2]; a.w = pin[4u * j4 + 3];
        return a;
    };

    float4 nb = make_float4(0.f, 0.f, 0.f, 0.f);
    #pragma unroll
    for (int p = 19; p >= 2; --p) {
        float4 v = ld4(i4 ^ (1u << (p - 2)));
        nb.x += v.x; nb.y += v.y; nb.z += v.z; nb.w += v.w;
    }
    float4 own = ld4(i4);
    // p = 1: element e gets own element e^2
    nb.x += own.z; nb.y += own.w; nb.z += own.x; nb.w += own.y;
    // p = 0: element e gets own element e^1
    nb.x += own.y; nb.y += own.x; nb.z += own.w; nb.w += own.z;

    float4 m;
    m.x = prevscale * fmaf(s, nb.x, own.x);
    m.y = prevscale * fmaf(s, nb.y, own.y);
    m.z = prevscale * fmaf(s, nb.z, own.z);
    m.w = prevscale * fmaf(s, nb.w, own.w);

    float4 o;
    if (LAYER < 2) {
        float gn = gamma[LAYER + 1];
        float4 c = ((const float4*)costs)[i4];
        o.x = m.x * cosf(gn * c.x);
        o.y = m.y * cosf(gn * c.y);
        o.z = m.z * cosf(gn * c.z);
        o.w = m.w * cosf(gn * c.w);
    } else {
        o = m;
    }
    if (ALOUT) {
        ((float4*)pout)[i4] = o;
    } else {
        pout[4u * i4 + 0] = o.x; pout[4u * i4 + 1] = o.y;
        pout[4u * i4 + 2] = o.z; pout[4u * i4 + 3] = o.w;
    }

    double ss = (double)m.x * m.x + (double)m.y * m.y +
                (double)m.z * m.z + (double)m.w * m.w;
    #pragma unroll
    for (int off = 32; off > 0; off >>= 1) ss += __shfl_down(ss, off);
    __shared__ double dpart[4];
    int wid = threadIdx.x >> 6;
    if ((threadIdx.x & 63) == 0) dpart[wid] = ss;
    __syncthreads();
    if (threadIdx.x == 0)
        atomicAdd(&scal[LAYER], dpart[0] + dpart[1] + dpart[2] + dpart[3]);
}

// ---------------------------------------------------------------------------
// Fused probs + top-k stage 1 + (last block) stage 2 merge & readout.
// 256 blocks x 256 threads, 16 elems/thread. probs[i] = (a[i]*scale)^2
// written to d_out; per-segment top-10 via packed (valbits<<32)|(~idx) keys
// (max key == max value, ties -> lower index, matching jax.lax.top_k).
// Last-arriving block (device-scope ticket) merges the 2560 candidates and
// emits top_assignments, assignment_costs, optimal_{assignment,cost}.
// ---------------------------------------------------------------------------
template <bool ALIN>
__global__ __launch_bounds__(256) void k_ptop(const float* __restrict__ A,
                                              const double* __restrict__ scal2,
                                              const float* __restrict__ costs,
                                              float* __restrict__ out,
                                              unsigned long long* __restrict__ cand,
                                              unsigned* __restrict__ ctr) {
    __shared__ unsigned long long warr[4];
    __shared__ int lastblk;
    __shared__ unsigned topi[TOPK];
    __shared__ float topc[TOPK];
    const int tid = threadIdx.x;
    float* probs_out = out + 21;
    unsigned b4 = blockIdx.x * 1024u;   // float4 base
    float scale = (float)(1.0 / sqrt(*scal2));

    unsigned long long k[16];
    #pragma unroll
    for (int u = 0; u < 4; ++u) {
        unsigned j4 = b4 + (unsigned)tid + 256u * u;
        float4 v;
        if (ALIN) v = ((const float4*)A)[j4];
        else {
            v.x = A[4u * j4 + 0]; v.y = A[4u * j4 + 1];
            v.z = A[4u * j4 + 2]; v.w = A[4u * j4 + 3];
        }
        float4 p;
        p.x = v.x * scale; p.x *= p.x;
        p.y = v.y * scale; p.y *= p.y;
        p.z = v.z * scale; p.z *= p.z;
        p.w = v.w * scale; p.w *= p.w;
        unsigned e0 = 4u * j4;
        probs_out[e0 + 0] = p.x; probs_out[e0 + 1] = p.y;
        probs_out[e0 + 2] = p.z; probs_out[e0 + 3] = p.w;
        k[4 * u + 0] = ((unsigned long long)__float_as_uint(p.x) << 32) | (unsigned long long)(0xFFFFFFFFu - (e0 + 0));
        k[4 * u + 1] = ((unsigned long long)__float_as_uint(p.y) << 32) | (unsigned long long)(0xFFFFFFFFu - (e0 + 1));
        k[4 * u + 2] = ((unsigned long long)__float_as_uint(p.z) << 32) | (unsigned long long)(0xFFFFFFFFu - (e0 + 2));
        k[4 * u + 3] = ((unsigned long long)__float_as_uint(p.w) << 32) | (unsigned long long)(0xFFFFFFFFu - (e0 + 3));
    }

    for (int r = 0; r < TOPK; ++r) {
        unsigned long long loc = 0ull;
        #pragma unroll
        for (int j = 0; j < 16; ++j) if (k[j] > loc) loc = k[j];
        #pragma unroll
        for (int off = 32; off > 0; off >>= 1) {
            unsigned long long o = __shfl_down(loc, off);
            if (o > loc) loc = o;
        }
        if ((tid & 63) == 0) warr[tid >> 6] = loc;
        __syncthreads();
        unsigned long long win = warr[0];
        if (warr[1] > win) win = warr[1];
        if (warr[2] > win) win = warr[2];
        if (warr[3] > win) win = warr[3];
        __syncthreads();
        #pragma unroll
        for (int j = 0; j < 16; ++j) if (k[j] == win) k[j] = 0ull;
        if (tid == 0) cand[blockIdx.x * TOPK + r] = win;
    }

    // ---- last-block ticket ----
    __threadfence();
    if (tid == 0) {
        unsigned old = atomicAdd(ctr, 1u);
        lastblk = (old == NB1 - 1) ? 1 : 0;
    }
    __syncthreads();
    if (!lastblk) return;
    __threadfence();

    // ---- stage 2: merge NCAND candidates with this one block ----
    unsigned long long c2[TOPK];
    #pragma unroll
    for (int u = 0; u < TOPK; ++u) c2[u] = cand[tid + 256 * u];

    for (int r = 0; r < TOPK; ++r) {
        unsigned long long loc = 0ull;
        #pragma unroll
        for (int u = 0; u < TOPK; ++u) if (c2[u] > loc) loc = c2[u];
        #pragma unroll
        for (int off = 32; off > 0; off >>= 1) {
            unsigned long long o = __shfl_down(loc, off);
            if (o > loc) loc = o;
        }
        if ((tid & 63) == 0) warr[tid >> 6] = loc;
        __syncthreads();
        unsigned long long win = warr[0];
        if (warr[1] > win) win = warr[1];
        if (warr[2] > win) win = warr[2];
        if (warr[3] > win) win = warr[3];
        __syncthreads();
        #pragma unroll
        for (int u = 0; u < TOPK; ++u) if (c2[u] == win) c2[u] = 0ull;
        if (tid == 0) topi[r] = 0xFFFFFFFFu - (unsigned)(win & 0xFFFFFFFFull);
        __syncthreads();
    }

    const unsigned S = NSTATES;
    if (tid < TOPK * NV) {
        int kk = tid / NV, vv = tid % NV;
        out[21 + S + (unsigned)tid] = (float)((topi[kk] >> (NV - 1 - vv)) & 1u);
    }
    if (tid < TOPK) {
        float c = costs[topi[tid]];
        topc[tid] = c;
        out[21 + S + TOPK * NV + (unsigned)tid] = c;
    }
    __syncthreads();
    if (tid == 0) {
        int best = 0;
        for (int kk = 1; kk < TOPK; ++kk)
            if (topc[kk] < topc[best]) best = kk;
        unsigned gi = topi[best];
        for (int vv = 0; vv < NV; ++vv)
            out[vv] = (float)((gi >> (NV - 1 - vv)) & 1u);
        out[NV] = topc[best];
    }
}

extern "C" void kernel_launch(void* const* d_in, const int* in_sizes, int n_in,
                              void* d_out_, int out_size, void* d_ws, size_t ws_size,
                              hipStream_t stream) {
    (void)in_sizes; (void)n_in; (void)out_size;
    const float* C     = (const float*)d_in[0];
    const float* beta  = (const float*)d_in[1];
    const float* gamma = (const float*)d_in[2];
    float* out = (float*)d_out_;
    char* ws = (char*)d_ws;
    const size_t S4 = (size_t)NSTATES * sizeof(float);

    double* scal = (double*)ws;                                   // 8 doubles
    unsigned* ctr = (unsigned*)(ws + 64);
    unsigned long long* cand = (unsigned long long*)(ws + 1024);  // 20 KB
    float* costs = (float*)(ws + 32768);
    float* A     = (float*)(ws + 32768 + S4);                     // ph0 / pm2
    const size_t need_full = 32768 + 3 * S4;
    bool wsbig = (ws_size >= need_full);
    float* B = wsbig ? (float*)(ws + 32768 + 2 * S4) : (out + 21); // pm1 / m2

    // costs + layer-0 phase array (A = ph0)
    k_costs<<<512, 256, 0, stream>>>(C, costs, A, gamma, scal, ctr);

    // mix0: A(ph0) -> B(pm1);  mix1: B(pm1) -> A(pm2);  mix2: A(pm2) -> B(m2)
    if (wsbig) {
        k_mix<0, true, true ><<<1024, 256, 0, stream>>>(A, costs, B, gamma, beta, scal);
        k_mix<1, true, true ><<<1024, 256, 0, stream>>>(B, costs, A, gamma, beta, scal);
        k_mix<2, true, true ><<<1024, 256, 0, stream>>>(A, costs, B, gamma, beta, scal);
        k_ptop<true ><<<NB1, 256, 0, stream>>>(B, scal + 2, costs, out, cand, ctr);
    } else {
        k_mix<0, true, false><<<1024, 256, 0, stream>>>(A, costs, B, gamma, beta, scal);
        k_mix<1, false, true><<<1024, 256, 0, stream>>>(B, costs, A, gamma, beta, scal);
        k_mix<2, true, false><<<1024, 256, 0, stream>>>(A, costs, B, gamma, beta, scal);
        k_ptop<false><<<NB1, 256, 0, stream>>>(B, scal + 2, costs, out, cand, ctr);
    }
}

// Round 4
// 89.554 us; speedup vs baseline: 3.4794x; 1.2577x over previous
//
#include <hip/hip_runtime.h>
#include <math.h>

#define NV 20
#define NC 64
#define NSTATES (1u << 20)
#define TOPK 10
#define NB1 256              // stage-1 top-k blocks
#define NCAND (NB1 * TOPK)   // 2560

// ---------------------------------------------------------------------------
// costs[i] = sum_c relu(bits(i)·C_c - 1)^2 + 0.1*popcount(i)
// Also emits ph0[i] = 2^-10 * cos(gamma0 * costs[i]) and zeroes the sumsq
// accumulators + the top-k ticket counter. Validated structure (3e-8).
// ---------------------------------------------------------------------------
__global__ __launch_bounds__(256) void k_costs(const float* __restrict__ C,
                                               float* __restrict__ costs,
                                               float* __restrict__ ph0,
                                               const float* __restrict__ gamma,
                                               double* __restrict__ scal,
                                               unsigned* __restrict__ ctr) {
    __shared__ float CT[NV][NC];    // CT[j][c] = C[c][j], 5 KB
    __shared__ float lowT[8][NC];   // low 3 bits (cols 19,18,17), 2 KB
    const int tid = threadIdx.x;

    if (blockIdx.x == 0) {
        if (tid < 8) scal[tid] = 0.0;
        if (tid == 8) *ctr = 0u;
    }

    for (int e = tid; e < NC * NV; e += 256) {
        int c = e / NV, j = e % NV;
        CT[j][c] = C[e];
    }
    for (int e = tid; e < 8 * NC; e += 256) {
        int m = e >> 6, c = e & 63;
        float v = 0.0f;
        if (m & 1) v += C[c * NV + 19];
        if (m & 2) v += C[c * NV + 18];
        if (m & 4) v += C[c * NV + 17];
        lowT[m][c] = v;
    }
    __syncthreads();

    unsigned t = blockIdx.x * 256u + (unsigned)tid;   // < 2^17
    float g0 = gamma[0];

    float4 b[16];
    #pragma unroll
    for (int q = 0; q < 16; ++q) b[q] = make_float4(-1.f, -1.f, -1.f, -1.f);
    #pragma unroll
    for (int k = 0; k < 17; ++k) {
        float bf = (float)((t >> k) & 1u);           // i-bit (k+3) -> col 16-k
        const float4* row = (const float4*)(&CT[16 - k][0]);
        #pragma unroll
        for (int q = 0; q < 16; ++q) {
            float4 cv = row[q];
            b[q].x = fmaf(bf, cv.x, b[q].x);
            b[q].y = fmaf(bf, cv.y, b[q].y);
            b[q].z = fmaf(bf, cv.z, b[q].z);
            b[q].w = fmaf(bf, cv.w, b[q].w);
        }
    }

    float res[8], ph[8];
    #pragma unroll
    for (int s = 0; s < 8; ++s) {
        unsigned i = t * 8u + (unsigned)s;
        float cost = 0.1f * (float)__popc(i);
        const float4* lrow = (const float4*)(&lowT[s][0]);
        #pragma unroll
        for (int q = 0; q < 16; ++q) {
            float4 lv = lrow[q];
            float4 v;
            v.x = b[q].x + lv.x; v.y = b[q].y + lv.y;
            v.z = b[q].z + lv.z; v.w = b[q].w + lv.w;
            float r;
            r = fmaxf(v.x, 0.f); cost = fmaf(r, r, cost);
            r = fmaxf(v.y, 0.f); cost = fmaf(r, r, cost);
            r = fmaxf(v.z, 0.f); cost = fmaf(r, r, cost);
            r = fmaxf(v.w, 0.f); cost = fmaf(r, r, cost);
        }
        res[s] = cost;
        ph[s] = 0x1p-10f * cosf(g0 * cost);
    }
    float4* co = (float4*)(costs + (size_t)t * 8u);
    co[0] = make_float4(res[0], res[1], res[2], res[3]);
    co[1] = make_float4(res[4], res[5], res[6], res[7]);
    float4* po = (float4*)(ph0 + (size_t)t * 8u);
    po[0] = make_float4(ph[0], ph[1], ph[2], ph[3]);
    po[1] = make_float4(ph[4], ph[5], ph[6], ph[7]);
}

// ---------------------------------------------------------------------------
// LDS-tiled mixer over pre-phased pin:
//   m[i]  = prevscale * (pin[i] + s*sum_{p=19..0} pin[i^(1<<p)])
//   LAYER<2: pout = m*cos(gamma[L+1]*costs);  LAYER==2: pout = m
// Block = 4096 contiguous elems (1024 quads, 16 KB LDS). Flips p=2..11 read
// the LDS tile (quad-index XOR, conflict-free b128); p=0,1 are in-quad
// swizzles; only p=12..19 gather globally. Accumulation order p=19..0
// descending — bitwise identical to the validated R3 kernel.
// ---------------------------------------------------------------------------
template <int LAYER, bool ALIN, bool ALOUT>
__global__ __launch_bounds__(1024, 4) void k_mix(const float* __restrict__ pin,
                                                 const float* __restrict__ costs,
                                                 float* __restrict__ pout,
                                                 const float* __restrict__ gamma,
                                                 const float* __restrict__ beta,
                                                 double* __restrict__ scal) {
    __shared__ float4 tile[1024];     // 16 KB
    __shared__ double dpart[16];
    const unsigned lq = threadIdx.x;               // local quad 0..1023
    const unsigned i4 = blockIdx.x * 1024u + lq;   // global quad < 2^18
    float s = 0.1f * sinf(beta[LAYER]);
    float prevscale = (LAYER == 0) ? 1.0f : (float)(1.0 / sqrt(scal[LAYER - 1]));

    auto ld4 = [&](unsigned j4) -> float4 {
        if (ALIN) return ((const float4*)pin)[j4];
        float4 a;
        a.x = pin[4u * j4 + 0]; a.y = pin[4u * j4 + 1];
        a.z = pin[4u * j4 + 2]; a.w = pin[4u * j4 + 3];
        return a;
    };

    float4 own = ld4(i4);
    tile[lq] = own;

    // issue the 8 far gathers (p = 19..12) before the barrier
    float4 gv[8];
    #pragma unroll
    for (int p = 19; p >= 12; --p) gv[19 - p] = ld4(i4 ^ (1u << (p - 2)));

    __syncthreads();

    float4 nb = make_float4(0.f, 0.f, 0.f, 0.f);
    #pragma unroll
    for (int u = 0; u < 8; ++u) {      // p = 19..12 descending
        nb.x += gv[u].x; nb.y += gv[u].y; nb.z += gv[u].z; nb.w += gv[u].w;
    }
    #pragma unroll
    for (int p = 11; p >= 2; --p) {    // local flips from LDS
        float4 v = tile[lq ^ (1u << (p - 2))];
        nb.x += v.x; nb.y += v.y; nb.z += v.z; nb.w += v.w;
    }
    // p = 1: element e gets own element e^2
    nb.x += own.z; nb.y += own.w; nb.z += own.x; nb.w += own.y;
    // p = 0: element e gets own element e^1
    nb.x += own.y; nb.y += own.x; nb.z += own.w; nb.w += own.z;

    float4 m;
    m.x = prevscale * fmaf(s, nb.x, own.x);
    m.y = prevscale * fmaf(s, nb.y, own.y);
    m.z = prevscale * fmaf(s, nb.z, own.z);
    m.w = prevscale * fmaf(s, nb.w, own.w);

    float4 o;
    if (LAYER < 2) {
        float gn = gamma[LAYER + 1];
        float4 c = ((const float4*)costs)[i4];
        o.x = m.x * cosf(gn * c.x);
        o.y = m.y * cosf(gn * c.y);
        o.z = m.z * cosf(gn * c.z);
        o.w = m.w * cosf(gn * c.w);
    } else {
        o = m;
    }
    if (ALOUT) {
        ((float4*)pout)[i4] = o;
    } else {
        pout[4u * i4 + 0] = o.x; pout[4u * i4 + 1] = o.y;
        pout[4u * i4 + 2] = o.z; pout[4u * i4 + 3] = o.w;
    }

    double ss = (double)m.x * m.x + (double)m.y * m.y +
                (double)m.z * m.z + (double)m.w * m.w;
    #pragma unroll
    for (int off = 32; off > 0; off >>= 1) ss += __shfl_down(ss, off);
    int wid = threadIdx.x >> 6;
    if ((threadIdx.x & 63) == 0) dpart[wid] = ss;
    __syncthreads();
    if (threadIdx.x == 0) {
        double t = 0.0;
        #pragma unroll
        for (int w = 0; w < 16; ++w) t += dpart[w];
        atomicAdd(&scal[LAYER], t);
    }
}

// ---------------------------------------------------------------------------
// Fused probs + top-k stage 1 + (last block) stage 2 merge & readout.
// ---------------------------------------------------------------------------
template <bool ALIN>
__global__ __launch_bounds__(256) void k_ptop(const float* __restrict__ A,
                                              const double* __restrict__ scal2,
                                              const float* __restrict__ costs,
                                              float* __restrict__ out,
                                              unsigned long long* __restrict__ cand,
                                              unsigned* __restrict__ ctr) {
    __shared__ unsigned long long warr[4];
    __shared__ int lastblk;
    __shared__ unsigned topi[TOPK];
    __shared__ float topc[TOPK];
    const int tid = threadIdx.x;
    float* probs_out = out + 21;
    unsigned b4 = blockIdx.x * 1024u;   // float4 base
    float scale = (float)(1.0 / sqrt(*scal2));

    unsigned long long k[16];
    #pragma unroll
    for (int u = 0; u < 4; ++u) {
        unsigned j4 = b4 + (unsigned)tid + 256u * u;
        float4 v;
        if (ALIN) v = ((const float4*)A)[j4];
        else {
            v.x = A[4u * j4 + 0]; v.y = A[4u * j4 + 1];
            v.z = A[4u * j4 + 2]; v.w = A[4u * j4 + 3];
        }
        float4 p;
        p.x = v.x * scale; p.x *= p.x;
        p.y = v.y * scale; p.y *= p.y;
        p.z = v.z * scale; p.z *= p.z;
        p.w = v.w * scale; p.w *= p.w;
        unsigned e0 = 4u * j4;
        probs_out[e0 + 0] = p.x; probs_out[e0 + 1] = p.y;
        probs_out[e0 + 2] = p.z; probs_out[e0 + 3] = p.w;
        k[4 * u + 0] = ((unsigned long long)__float_as_uint(p.x) << 32) | (unsigned long long)(0xFFFFFFFFu - (e0 + 0));
        k[4 * u + 1] = ((unsigned long long)__float_as_uint(p.y) << 32) | (unsigned long long)(0xFFFFFFFFu - (e0 + 1));
        k[4 * u + 2] = ((unsigned long long)__float_as_uint(p.z) << 32) | (unsigned long long)(0xFFFFFFFFu - (e0 + 2));
        k[4 * u + 3] = ((unsigned long long)__float_as_uint(p.w) << 32) | (unsigned long long)(0xFFFFFFFFu - (e0 + 3));
    }

    for (int r = 0; r < TOPK; ++r) {
        unsigned long long loc = 0ull;
        #pragma unroll
        for (int j = 0; j < 16; ++j) if (k[j] > loc) loc = k[j];
        #pragma unroll
        for (int off = 32; off > 0; off >>= 1) {
            unsigned long long o = __shfl_down(loc, off);
            if (o > loc) loc = o;
        }
        if ((tid & 63) == 0) warr[tid >> 6] = loc;
        __syncthreads();
        unsigned long long win = warr[0];
        if (warr[1] > win) win = warr[1];
        if (warr[2] > win) win = warr[2];
        if (warr[3] > win) win = warr[3];
        __syncthreads();
        #pragma unroll
        for (int j = 0; j < 16; ++j) if (k[j] == win) k[j] = 0ull;
        if (tid == 0) cand[blockIdx.x * TOPK + r] = win;
    }

    // ---- last-block ticket ----
    __threadfence();
    if (tid == 0) {
        unsigned old = atomicAdd(ctr, 1u);
        lastblk = (old == NB1 - 1) ? 1 : 0;
    }
    __syncthreads();
    if (!lastblk) return;
    __threadfence();

    // ---- stage 2: merge NCAND candidates with this one block ----
    unsigned long long c2[TOPK];
    #pragma unroll
    for (int u = 0; u < TOPK; ++u) c2[u] = cand[tid + 256 * u];

    for (int r = 0; r < TOPK; ++r) {
        unsigned long long loc = 0ull;
        #pragma unroll
        for (int u = 0; u < TOPK; ++u) if (c2[u] > loc) loc = c2[u];
        #pragma unroll
        for (int off = 32; off > 0; off >>= 1) {
            unsigned long long o = __shfl_down(loc, off);
            if (o > loc) loc = o;
        }
        if ((tid & 63) == 0) warr[tid >> 6] = loc;
        __syncthreads();
        unsigned long long win = warr[0];
        if (warr[1] > win) win = warr[1];
        if (warr[2] > win) win = warr[2];
        if (warr[3] > win) win = warr[3];
        __syncthreads();
        #pragma unroll
        for (int u = 0; u < TOPK; ++u) if (c2[u] == win) c2[u] = 0ull;
        if (tid == 0) topi[r] = 0xFFFFFFFFu - (unsigned)(win & 0xFFFFFFFFull);
        __syncthreads();
    }

    const unsigned S = NSTATES;
    if (tid < TOPK * NV) {
        int kk = tid / NV, vv = tid % NV;
        out[21 + S + (unsigned)tid] = (float)((topi[kk] >> (NV - 1 - vv)) & 1u);
    }
    if (tid < TOPK) {
        float c = costs[topi[tid]];
        topc[tid] = c;
        out[21 + S + TOPK * NV + (unsigned)tid] = c;
    }
    __syncthreads();
    if (tid == 0) {
        int best = 0;
        for (int kk = 1; kk < TOPK; ++kk)
            if (topc[kk] < topc[best]) best = kk;
        unsigned gi = topi[best];
        for (int vv = 0; vv < NV; ++vv)
            out[vv] = (float)((gi >> (NV - 1 - vv)) & 1u);
        out[NV] = topc[best];
    }
}

extern "C" void kernel_launch(void* const* d_in, const int* in_sizes, int n_in,
                              void* d_out_, int out_size, void* d_ws, size_t ws_size,
                              hipStream_t stream) {
    (void)in_sizes; (void)n_in; (void)out_size;
    const float* C     = (const float*)d_in[0];
    const float* beta  = (const float*)d_in[1];
    const float* gamma = (const float*)d_in[2];
    float* out = (float*)d_out_;
    char* ws = (char*)d_ws;
    const size_t S4 = (size_t)NSTATES * sizeof(float);

    double* scal = (double*)ws;                                   // 8 doubles
    unsigned* ctr = (unsigned*)(ws + 64);
    unsigned long long* cand = (unsigned long long*)(ws + 1024);  // 20 KB
    float* costs = (float*)(ws + 32768);
    float* A     = (float*)(ws + 32768 + S4);                     // ph0 / pm2
    const size_t need_full = 32768 + 3 * S4;
    bool wsbig = (ws_size >= need_full);
    float* B = wsbig ? (float*)(ws + 32768 + 2 * S4) : (out + 21); // pm1 / m2

    // costs + layer-0 phase array (A = ph0)
    k_costs<<<512, 256, 0, stream>>>(C, costs, A, gamma, scal, ctr);

    // mix0: A(ph0) -> B(pm1);  mix1: B(pm1) -> A(pm2);  mix2: A(pm2) -> B(m2)
    if (wsbig) {
        k_mix<0, true, true ><<<256, 1024, 0, stream>>>(A, costs, B, gamma, beta, scal);
        k_mix<1, true, true ><<<256, 1024, 0, stream>>>(B, costs, A, gamma, beta, scal);
        k_mix<2, true, true ><<<256, 1024, 0, stream>>>(A, costs, B, gamma, beta, scal);
        k_ptop<true ><<<NB1, 256, 0, stream>>>(B, scal + 2, costs, out, cand, ctr);
    } else {
        k_mix<0, true, false><<<256, 1024, 0, stream>>>(A, costs, B, gamma, beta, scal);
        k_mix<1, false, true><<<256, 1024, 0, stream>>>(B, costs, A, gamma, beta, scal);
        k_mix<2, true, false><<<256, 1024, 0, stream>>>(A, costs, B, gamma, beta, scal);
        k_ptop<false><<<NB1, 256, 0, stream>>>(B, scal + 2, costs, out, cand, ctr);
    }
}